// Round 13
// baseline (728.819 us; speedup 1.0000x reference)
//
#include <hip/hip_runtime.h>

// GCNN via FFT over the cyclic group C_256 — 64-VGPR edition.
// Evidence R10-R12: 4 waves/SIMD on this chip requires VGPR <= 64; prior
// attempts spilled (64-reg GEMM accumulator + 16 regs of persistent trig).
// This version fits: (1) GEMM = one POSITION per lane pair, acc[16] (32 regs),
// mirror positions apply conj via sign-folded FMA (no conj-sharing, 2x weight
// loads, L2-hot); (2) per-lane trig in a global table (volatile loads each
// FFT phase -> never live across GEMM). Shell: 512 blocks x 512 threads,
// Zs[32][256] float2 = 65536 B exactly, launch_bounds(512,4) -> 2 blocks/CU.

#define NG 256
#define NLAYER 3

__device__ __forceinline__ int brv6(int x) { return (int)(__brev((unsigned)x) >> 26); }

// ---------------- LDS FFT machinery (used ONLY by gcnn_wfft) ----------------
__device__ __forceinline__ int swz(int a) {
  int h = a >> 4;
  return a ^ ((h ^ (h << 1)) & 15);
}

__device__ __forceinline__ void wave_fft256_lds(float2* __restrict__ s,
                                                const float2* __restrict__ tw,
                                                int lane) {
  asm volatile("s_waitcnt lgkmcnt(0)" ::: "memory");
  #pragma unroll
  for (int t = 0; t < 4; ++t) {
    int i = t * 64 + lane;
    int j = (int)(__brev((unsigned)i) >> 24);
    if (j > i) {
      float2 a = s[swz(i)]; float2 b = s[swz(j)];
      s[swz(i)] = b; s[swz(j)] = a;
    }
  }
  asm volatile("s_waitcnt lgkmcnt(0)" ::: "memory");
  #pragma unroll
  for (int st = 0; st < 8; ++st) {
    const int half = 1 << st;
    const int tshift = 7 - st;
    #pragma unroll
    for (int t = 0; t < 2; ++t) {
      int bf = t * 64 + lane;
      int off = bf & (half - 1);
      int blk = bf >> st;
      int i = (blk << (st + 1)) + off;
      int j = i + half;
      float2 wv = tw[swz(off << tshift)];
      float2 u = s[swz(i)];
      float2 v = s[swz(j)];
      float vr = v.x * wv.x - v.y * wv.y;
      float vi = v.x * wv.y + v.y * wv.x;
      s[swz(i)] = make_float2(u.x + vr, u.y + vi);
      s[swz(j)] = make_float2(u.x - vr, u.y - vi);
    }
    asm volatile("s_waitcnt lgkmcnt(0)" ::: "memory");
  }
}

__device__ __forceinline__ float2 cadd(float2 a, float2 b) { return make_float2(a.x + b.x, a.y + b.y); }
__device__ __forceinline__ float2 csub(float2 a, float2 b) { return make_float2(a.x - b.x, a.y - b.y); }
__device__ __forceinline__ float2 cmul(float2 a, float2 b) {
  return make_float2(a.x * b.x - a.y * b.y, a.x * b.y + a.y * b.x);
}
__device__ __forceinline__ float2 cmulc(float2 a, float2 b) {  // a * conj(b)
  return make_float2(a.x * b.x + a.y * b.y, a.y * b.x - a.x * b.y);
}
__device__ __forceinline__ float2 shxor(float2 v, int m) {
  return make_float2(__shfl_xor(v.x, m), __shfl_xor(v.y, m));
}

// weight FFT prep + per-lane trig table Twl[64][8] = {tw0..tw4, u1, u2, u3}.
__global__ __launch_bounds__(256) void gcnn_wfft(
    const float* __restrict__ w_symm, const float* __restrict__ w_eq,
    float2* __restrict__ Ws_hat, float2* __restrict__ WeqM,
    float2* __restrict__ Weq128, float2* __restrict__ Twl) {
  __shared__ float2 fbw[4][256];
  __shared__ float2 twl[256];
  const int tid = threadIdx.x;
  const int w = tid >> 6;
  const int lane = tid & 63;
  {
    float a = (float)tid * 0.0245436926f;  // 2*pi/256
    twl[swz(tid)] = make_float2(cosf(a), -sinf(a));
  }
  __syncthreads();
  const int task = blockIdx.x * 4 + w;  // 776*4 = 3104 tasks exactly
  if (task < 32) {
    const int f = task;
    for (int g = lane; g < 256; g += 64)
      fbw[w][swz(g)] = make_float2(w_symm[g * 32 + f], 0.f);
    wave_fft256_lds(&fbw[w][0], twl, lane);
    for (int k = lane; k < 256; k += 64) {
      int pos = brv6(k & 63) | (k & 192);
      Ws_hat[f * 256 + pos] = fbw[w][swz(k)];
    }
  } else {
    const int idx = task - 32;
    const int l = idx >> 10;
    const int fi = (idx >> 5) & 31;
    const int fo = idx & 31;
    for (int g = lane; g < 256; g += 64)
      fbw[w][swz(g)] = make_float2(w_eq[((size_t)(l * 256 + g) * 32 + fi) * 32 + fo] * (1.f / 256.f), 0.f);
    wave_fft256_lds(&fbw[w][0], twl, lane);
    for (int k = lane; k < 129; k += 64) {
      int sk = (k < 64) ? brv6(k) : ((k < 128) ? 64 + brv6(k - 64) : 128);
      if (sk < 128)
        WeqM[((size_t)((l * 32 + fi) * 128 + sk)) * 32 + fo] = fbw[w][swz(k)];
      else
        Weq128[(l * 32 + fi) * 32 + fo] = fbw[w][swz(k)];
    }
  }
  // per-lane FFT constants table (block 0, wave 0)
  if (blockIdx.x == 0 && tid < 64) {
    const int ln = tid;
    const int bv = brv6(ln);
    #pragma unroll
    for (int s = 0; s < 5; ++s) {
      const int half = 32 >> s;
      float ang = -0.09817477042468103871f * (float)((ln & (half - 1)) << s);
      float sv, cv; __sincosf(ang, &sv, &cv);
      Twl[ln * 8 + s] = make_float2(cv, sv);
    }
    float ang = -0.02454369260617025968f * (float)bv;
    float sv, cv; __sincosf(ang, &sv, &cv);
    float2 u1 = make_float2(cv, sv);
    float2 u2 = cmul(u1, u1);
    Twl[ln * 8 + 5] = u1;
    Twl[ln * 8 + 6] = u2;
    Twl[ln * 8 + 7] = cmul(u2, u1);
  }
}

// ---------------- register FFT machinery (verified rounds 4-12, absmax 0) ----------------
// Forward: T {z[r]=x[4*lane+r]} -> S {z[r]=X[bitrev6(lane)+64r]}
__device__ __forceinline__ void fwd256(float2 z[4], const float2 tw[5],
                                       float2 u1, float2 u2, float2 u3, int lane) {
  #pragma unroll
  for (int s = 0; s < 6; ++s) {
    const int half = 32 >> s;
    const bool bot = (lane & half) != 0;
    #pragma unroll
    for (int r = 0; r < 4; ++r) {
      float2 o = shxor(z[r], half);
      float2 sum = cadd(z[r], o);
      float2 dif = csub(o, z[r]);
      float2 bo = (s < 5) ? cmul(dif, tw[s]) : dif;
      z[r] = bot ? bo : sum;
    }
  }
  z[1] = cmul(z[1], u1);
  z[2] = cmul(z[2], u2);
  z[3] = cmul(z[3], u3);
  float2 t0 = cadd(z[0], z[2]), t1 = cadd(z[1], z[3]);
  float2 t2 = csub(z[0], z[2]), t3 = csub(z[1], z[3]);
  z[0] = cadd(t0, t1);
  z[2] = csub(t0, t1);
  z[1] = make_float2(t2.x + t3.y, t2.y - t3.x);
  z[3] = make_float2(t2.x - t3.y, t2.y + t3.x);
}

// Inverse (unnormalized): S -> T
__device__ __forceinline__ void inv256(float2 z[4], const float2 tw[5],
                                       float2 u1, float2 u2, float2 u3, int lane) {
  float2 t0 = cadd(z[0], z[2]), t1 = cadd(z[1], z[3]);
  float2 t2 = csub(z[0], z[2]), t3 = csub(z[1], z[3]);
  z[0] = cadd(t0, t1);
  z[2] = csub(t0, t1);
  z[1] = make_float2(t2.x - t3.y, t2.y + t3.x);
  z[3] = make_float2(t2.x + t3.y, t2.y - t3.x);
  z[1] = cmulc(z[1], u1);
  z[2] = cmulc(z[2], u2);
  z[3] = cmulc(z[3], u3);
  #pragma unroll
  for (int s = 5; s >= 0; --s) {
    const int half = 32 >> s;
    const bool bot = (lane & half) != 0;
    #pragma unroll
    for (int r = 0; r < 4; ++r) {
      float2 m = (s < 5 && bot) ? cmulc(z[r], tw[s]) : z[r];
      float2 o = shxor(m, half);
      z[r] = bot ? csub(o, m) : cadd(o, m);
    }
  }
}

__device__ __forceinline__ float swishf(float y) { return y / (1.f + __expf(-y)); }

// volatile (un-hoistable) load of a float2 from the trig table
__device__ __forceinline__ float2 vload2(const float2* p) {
  const volatile float* q = (const volatile float*)p;
  float x = q[0];
  float y = q[1];
  return make_float2(x, y);
}

// ---------------- main fused kernel: 512 blocks x 512 threads, 1 pair (2 rows) ----------------
__global__ __launch_bounds__(512, 4) void gcnn_main(
    const float* __restrict__ x_in, const float* __restrict__ b_symm,
    const float* __restrict__ b_eq, const float2* __restrict__ Ws_hat,
    const float2* __restrict__ WeqM, const float2* __restrict__ Weq128,
    const float2* __restrict__ Twl, float* __restrict__ out) {
  __shared__ float2 Zs[32 * 256];   // [fi][pos], 65536 bytes EXACTLY

  const int tid = threadIdx.x;
  const int w = tid >> 6;
  const int lane = tid & 63;
  const int brev = brv6(lane);
  const int rbl = brv6((64 - brev) & 63);   // mirror lane (for lane != 0)

  // Phase 0a: wave0 packs 2 rows, FFTs, mirrors in regs, stashes into row 31
  if (w == 0) {
    float2 tws[5], tu1, tu2, tu3;
    #pragma unroll
    for (int s = 0; s < 5; ++s) tws[s] = vload2(Twl + lane * 8 + s);
    tu1 = vload2(Twl + lane * 8 + 5);
    tu2 = vload2(Twl + lane * 8 + 6);
    tu3 = vload2(Twl + lane * 8 + 7);
    const float* xa = x_in + (size_t)blockIdx.x * 2 * NG;
    float4 va = reinterpret_cast<const float4*>(xa)[lane];
    float4 vb = reinterpret_cast<const float4*>(xa + NG)[lane];
    float2 z[4] = {{va.x, vb.x}, {va.y, vb.y}, {va.z, vb.z}, {va.w, vb.w}};
    fwd256(z, tws, tu1, tu2, tu3, lane);
    float2 mz[4];
    #pragma unroll
    for (int r = 0; r < 4; ++r) {
      float2 g = make_float2(__shfl(z[3 - r].x, rbl), __shfl(z[3 - r].y, rbl));
      mz[r] = g;
    }
    if (lane == 0) {
      float2 own[4] = {z[0], z[1], z[2], z[3]};
      #pragma unroll
      for (int r = 0; r < 4; ++r) mz[r] = own[(4 - r) & 3];
    }
    #pragma unroll
    for (int r = 0; r < 4; ++r) Zs[31 * 256 + lane + (r << 6)] = mz[r];
  }
  __syncthreads();

  // Phase 0b: Z0[f][s] = ZxMirror[s] * WsHat[f][s] (+256*bs*(1+i) at s=0)
  {
    float2 keep[4];
    #pragma unroll
    for (int j = 0; j < 4; ++j) {
      const int f = w + 8 * j;
      const float bs = 256.f * b_symm[f];
      const float2* wsf = Ws_hat + f * 256;
      float2 o[4];
      #pragma unroll
      for (int r = 0; r < 4; ++r) {
        const int s = lane + (r << 6);
        float2 m = Zs[31 * 256 + s];
        o[r] = cmul(m, wsf[s]);
        if (s == 0) { o[r].x += bs; o[r].y += bs; }
      }
      if (f == 31) {
        #pragma unroll
        for (int r = 0; r < 4; ++r) keep[r] = o[r];
      } else {
        #pragma unroll
        for (int r = 0; r < 4; ++r) Zs[f * 256 + lane + (r << 6)] = o[r];
      }
    }
    __syncthreads();   // all reads of temp row 31 complete
    if (w == 7) {
      #pragma unroll
      for (int r = 0; r < 4; ++r) Zs[31 * 256 + lane + (r << 6)] = keep[r];
    }
  }
  __syncthreads();

  #pragma unroll 1
  for (int l = 0; l < NLAYER; ++l) {
    const bool last = (l == NLAYER - 1);

    // ---- spectral GEMM on packed Z: lane pair = one position, acc[16] ----
    {
      const int pos = tid >> 1;    // 0..255 (S-layout position)
      const int hf = tid & 1;      // fo half
      float2 acc[16];
      #pragma unroll
      for (int j = 0; j < 16; ++j) acc[j] = make_float2(0.f, 0.f);
      if (pos == 128) {
        // bin 128 (self-conjugate), separate weight slab
        const float2* wb = Weq128 + l * 1024 + hf * 16;
        #pragma unroll 2
        for (int fi = 0; fi < 32; ++fi) {
          float2 h = Zs[fi * 256 + 128];
          const float4* wp = reinterpret_cast<const float4*>(wb + fi * 32);
          #pragma unroll
          for (int q = 0; q < 8; ++q) {
            float4 v = wp[q];
            acc[2 * q].x     += h.x * v.x - h.y * v.y;
            acc[2 * q].y     += h.x * v.y + h.y * v.x;
            acc[2 * q + 1].x += h.x * v.z - h.y * v.w;
            acc[2 * q + 1].y += h.x * v.w + h.y * v.z;
          }
        }
      } else {
        const bool cj = pos > 128;      // mirror region: multiply by conj(w)
        int kp;
        if (!cj) kp = pos;
        else {
          const int ll = pos & 63, rr = pos >> 6;
          kp = (ll == 0) ? (256 - pos)
                         : (brv6((64 - brv6(ll)) & 63) + ((3 - rr) << 6));
        }
        const float sg = cj ? -1.f : 1.f;
        #pragma unroll 2
        for (int fi = 0; fi < 32; ++fi) {
          float2 h = Zs[fi * 256 + pos];
          const float hxs = sg * h.x, hys = sg * h.y;
          const float4* wp = reinterpret_cast<const float4*>(
              WeqM + ((size_t)((l * 32 + fi) * 128 + kp)) * 32 + hf * 16);
          #pragma unroll
          for (int q = 0; q < 8; ++q) {
            float4 v = wp[q];
            acc[2 * q].x     += h.x * v.x - hys * v.y;
            acc[2 * q].y     += hxs * v.y + h.y * v.x;
            acc[2 * q + 1].x += h.x * v.z - hys * v.w;
            acc[2 * q + 1].y += hxs * v.w + h.y * v.z;
          }
        }
        if (pos == 0) {
          #pragma unroll
          for (int j = 0; j < 16; ++j) {
            float be = b_eq[l * 32 + hf * 16 + j];
            acc[j].x += be;   // bias hits both packed rows at bin 0
            acc[j].y += be;
          }
        }
      }
      // write back: column pos is private to this lane pair (same wave,
      // lockstep: both lanes' fi-loop reads complete before any write)
      #pragma unroll
      for (int j = 0; j < 16; ++j)
        Zs[(hf * 16 + j) * 256 + pos] = acc[j];
    }
    __syncthreads();

    // ---- per feature: IFFT -> swish -> (FFT+store | reduce) ----
    float ls0 = 0.f, ls1 = 0.f;
    {
      float2 tws[5], tu1, tu2, tu3;
      #pragma unroll
      for (int s = 0; s < 5; ++s) tws[s] = vload2(Twl + lane * 8 + s);
      tu1 = vload2(Twl + lane * 8 + 5);
      tu2 = vload2(Twl + lane * 8 + 6);
      tu3 = vload2(Twl + lane * 8 + 7);
      #pragma unroll 1
      for (int j = 0; j < 4; ++j) {
        const int f = w + 8 * j;
        float2* zrow = Zs + f * 256;
        float2 z[4];
        #pragma unroll
        for (int r = 0; r < 4; ++r) z[r] = zrow[lane + (r << 6)];
        inv256(z, tws, tu1, tu2, tu3, lane);  // z[r] = (rowA[4lane+r], rowB[4lane+r])
        if (!last) {
          #pragma unroll
          for (int r = 0; r < 4; ++r) {
            z[r].x = swishf(z[r].x);
            z[r].y = swishf(z[r].y);
          }
          fwd256(z, tws, tu1, tu2, tu3, lane);
          #pragma unroll
          for (int r = 0; r < 4; ++r) zrow[lane + (r << 6)] = z[r];
        } else {
          #pragma unroll
          for (int r = 0; r < 4; ++r) {
            ls0 += swishf(z[r].x);
            ls1 += swishf(z[r].y);
          }
        }
      }
    }
    if (last) {
      #pragma unroll
      for (int m = 32; m >= 1; m >>= 1) {
        ls0 += __shfl_xor(ls0, m);
        ls1 += __shfl_xor(ls1, m);
      }
      __syncthreads();                 // all waves done READING Zs
      if (lane == 0) Zs[w] = make_float2(ls0, ls1);   // red overlay on row 0
    }
    __syncthreads();
  }

  if (tid < 2) {
    float s = 0.f;
    #pragma unroll
    for (int ww = 0; ww < 8; ++ww)
      s += (tid == 0) ? Zs[ww].x : Zs[ww].y;
    out[blockIdx.x * 2 + tid] = s * (1.f / 8192.f);
  }
}

extern "C" void kernel_launch(void* const* d_in, const int* in_sizes, int n_in,
                              void* d_out, int out_size, void* d_ws, size_t ws_size,
                              hipStream_t stream) {
  const float* x_in   = (const float*)d_in[0];
  // d_in[1] = perms, d_in[2] = group_algebra: structure hard-coded (cyclic group)
  const float* w_symm = (const float*)d_in[3];
  const float* b_symm = (const float*)d_in[4];
  const float* w_eq   = (const float*)d_in[5];
  const float* b_eq   = (const float*)d_in[6];
  float* out = (float*)d_out;

  float2* Ws_hat = (float2*)d_ws;                      // 32*256
  float2* WeqM   = Ws_hat + 32 * 256;                  // 3*32*128*32
  float2* Weq128 = WeqM + (size_t)3 * 32 * 128 * 32;   // 3*32*32
  float2* Twl    = Weq128 + 3 * 32 * 32;               // 64*8  (~3.25 MB total)

  hipLaunchKernelGGL(gcnn_wfft, dim3(776), dim3(256), 0, stream,
                     w_symm, w_eq, Ws_hat, WeqM, Weq128, Twl);
  hipLaunchKernelGGL(gcnn_main, dim3(512), dim3(512), 0, stream,
                     x_in, b_symm, b_eq, Ws_hat, WeqM, Weq128, Twl, out);
}

// Round 14
// 422.767 us; speedup vs baseline: 1.7239x; 1.7239x over previous
//
#include <hip/hip_runtime.h>

// GCNN via FFT over C_256 — two-team software-pipelined edition.
// Block = 8 waves = 2 teams x 4 waves; team t owns packed pair t (2 batch
// rows, Z = rowA + i*rowB, 64KB slab). Teams run one phase apart:
//   slot: {T0: GEMM(l) | T1: FFT(l-1)} -> barrier -> swap ...
// so every SIMD co-schedules one VMEM-heavy GEMM wave with one DS/VALU-heavy
// FFT wave (complementary stalls). Per-lane work identical to R8 (177us).
// GEMM = R13's linear-position form (conj via sign-folded FMA, absmax-0
// proven, 4x fewer bank conflicts); two column-passes (pos<128, pos>=128)
// touch disjoint LDS columns -> no intra-team sync needed.

#define NG 256
#define NLAYER 3

__device__ __forceinline__ int brv6(int x) { return (int)(__brev((unsigned)x) >> 26); }

// ---------------- LDS FFT machinery (used ONLY by gcnn_wfft) ----------------
__device__ __forceinline__ int swz(int a) {
  int h = a >> 4;
  return a ^ ((h ^ (h << 1)) & 15);
}

__device__ __forceinline__ void wave_fft256_lds(float2* __restrict__ s,
                                                const float2* __restrict__ tw,
                                                int lane) {
  asm volatile("s_waitcnt lgkmcnt(0)" ::: "memory");
  #pragma unroll
  for (int t = 0; t < 4; ++t) {
    int i = t * 64 + lane;
    int j = (int)(__brev((unsigned)i) >> 24);
    if (j > i) {
      float2 a = s[swz(i)]; float2 b = s[swz(j)];
      s[swz(i)] = b; s[swz(j)] = a;
    }
  }
  asm volatile("s_waitcnt lgkmcnt(0)" ::: "memory");
  #pragma unroll
  for (int st = 0; st < 8; ++st) {
    const int half = 1 << st;
    const int tshift = 7 - st;
    #pragma unroll
    for (int t = 0; t < 2; ++t) {
      int bf = t * 64 + lane;
      int off = bf & (half - 1);
      int blk = bf >> st;
      int i = (blk << (st + 1)) + off;
      int j = i + half;
      float2 wv = tw[swz(off << tshift)];
      float2 u = s[swz(i)];
      float2 v = s[swz(j)];
      float vr = v.x * wv.x - v.y * wv.y;
      float vi = v.x * wv.y + v.y * wv.x;
      s[swz(i)] = make_float2(u.x + vr, u.y + vi);
      s[swz(j)] = make_float2(u.x - vr, u.y - vi);
    }
    asm volatile("s_waitcnt lgkmcnt(0)" ::: "memory");
  }
}

// weight FFT prep. Ws_hat: full 256 positions; WeqM: positions 0..127;
// Weq128: bin 128. (Identical to proven R8-R13 prep.)
__global__ __launch_bounds__(256) void gcnn_wfft(
    const float* __restrict__ w_symm, const float* __restrict__ w_eq,
    float2* __restrict__ Ws_hat, float2* __restrict__ WeqM,
    float2* __restrict__ Weq128) {
  __shared__ float2 fbw[4][256];
  __shared__ float2 twl[256];
  const int tid = threadIdx.x;
  const int w = tid >> 6;
  const int lane = tid & 63;
  {
    float a = (float)tid * 0.0245436926f;  // 2*pi/256
    twl[swz(tid)] = make_float2(cosf(a), -sinf(a));
  }
  __syncthreads();
  const int task = blockIdx.x * 4 + w;  // 776*4 = 3104 tasks exactly
  if (task < 32) {
    const int f = task;
    for (int g = lane; g < 256; g += 64)
      fbw[w][swz(g)] = make_float2(w_symm[g * 32 + f], 0.f);
    wave_fft256_lds(&fbw[w][0], twl, lane);
    for (int k = lane; k < 256; k += 64) {
      int pos = brv6(k & 63) | (k & 192);
      Ws_hat[f * 256 + pos] = fbw[w][swz(k)];
    }
  } else {
    const int idx = task - 32;
    const int l = idx >> 10;
    const int fi = (idx >> 5) & 31;
    const int fo = idx & 31;
    for (int g = lane; g < 256; g += 64)
      fbw[w][swz(g)] = make_float2(w_eq[((size_t)(l * 256 + g) * 32 + fi) * 32 + fo] * (1.f / 256.f), 0.f);
    wave_fft256_lds(&fbw[w][0], twl, lane);
    for (int k = lane; k < 129; k += 64) {
      int sk = (k < 64) ? brv6(k) : ((k < 128) ? 64 + brv6(k - 64) : 128);
      if (sk < 128)
        WeqM[((size_t)((l * 32 + fi) * 128 + sk)) * 32 + fo] = fbw[w][swz(k)];
      else
        Weq128[(l * 32 + fi) * 32 + fo] = fbw[w][swz(k)];
    }
  }
}

// ---------------- register FFT machinery (verified rounds 4-13, absmax 0) ----------------
__device__ __forceinline__ float2 cadd(float2 a, float2 b) { return make_float2(a.x + b.x, a.y + b.y); }
__device__ __forceinline__ float2 csub(float2 a, float2 b) { return make_float2(a.x - b.x, a.y - b.y); }
__device__ __forceinline__ float2 cmul(float2 a, float2 b) {
  return make_float2(a.x * b.x - a.y * b.y, a.x * b.y + a.y * b.x);
}
__device__ __forceinline__ float2 cmulc(float2 a, float2 b) {  // a * conj(b)
  return make_float2(a.x * b.x + a.y * b.y, a.y * b.x - a.x * b.y);
}
__device__ __forceinline__ float2 shxor(float2 v, int m) {
  return make_float2(__shfl_xor(v.x, m), __shfl_xor(v.y, m));
}

// Forward: T {z[r]=x[4*lane+r]} -> S {z[r]=X[bitrev6(lane)+64r]}
__device__ __forceinline__ void fwd256(float2 z[4], const float2 tw[5],
                                       float2 u1, float2 u2, float2 u3, int lane) {
  #pragma unroll
  for (int s = 0; s < 6; ++s) {
    const int half = 32 >> s;
    const bool bot = (lane & half) != 0;
    #pragma unroll
    for (int r = 0; r < 4; ++r) {
      float2 o = shxor(z[r], half);
      float2 sum = cadd(z[r], o);
      float2 dif = csub(o, z[r]);
      float2 bo = (s < 5) ? cmul(dif, tw[s]) : dif;
      z[r] = bot ? bo : sum;
    }
  }
  z[1] = cmul(z[1], u1);
  z[2] = cmul(z[2], u2);
  z[3] = cmul(z[3], u3);
  float2 t0 = cadd(z[0], z[2]), t1 = cadd(z[1], z[3]);
  float2 t2 = csub(z[0], z[2]), t3 = csub(z[1], z[3]);
  z[0] = cadd(t0, t1);
  z[2] = csub(t0, t1);
  z[1] = make_float2(t2.x + t3.y, t2.y - t3.x);
  z[3] = make_float2(t2.x - t3.y, t2.y + t3.x);
}

// Inverse (unnormalized): S -> T
__device__ __forceinline__ void inv256(float2 z[4], const float2 tw[5],
                                       float2 u1, float2 u2, float2 u3, int lane) {
  float2 t0 = cadd(z[0], z[2]), t1 = cadd(z[1], z[3]);
  float2 t2 = csub(z[0], z[2]), t3 = csub(z[1], z[3]);
  z[0] = cadd(t0, t1);
  z[2] = csub(t0, t1);
  z[1] = make_float2(t2.x - t3.y, t2.y + t3.x);
  z[3] = make_float2(t2.x + t3.y, t2.y - t3.x);
  z[1] = cmulc(z[1], u1);
  z[2] = cmulc(z[2], u2);
  z[3] = cmulc(z[3], u3);
  #pragma unroll
  for (int s = 5; s >= 0; --s) {
    const int half = 32 >> s;
    const bool bot = (lane & half) != 0;
    #pragma unroll
    for (int r = 0; r < 4; ++r) {
      float2 m = (s < 5 && bot) ? cmulc(z[r], tw[s]) : z[r];
      float2 o = shxor(m, half);
      z[r] = bot ? csub(o, m) : cadd(o, m);
    }
  }
}

__device__ __forceinline__ float swishf(float y) { return y / (1.f + __expf(-y)); }

// ---- team GEMM: 256 lanes cover 512 (pos,hf) units in two column-passes ----
__device__ __forceinline__ void teamGEMM(
    float2* __restrict__ zbase, const float2* __restrict__ WeqM,
    const float2* __restrict__ Weq128, const float* __restrict__ b_eq,
    int l, int tp) {
  #pragma unroll 1
  for (int pass = 0; pass < 2; ++pass) {
    const int pos = pass * 128 + (tp >> 1);
    const int hf = tp & 1;
    float2 acc[16];
    #pragma unroll
    for (int j = 0; j < 16; ++j) acc[j] = make_float2(0.f, 0.f);
    if (pos == 128) {
      const float2* wb = Weq128 + l * 1024 + hf * 16;
      #pragma unroll 2
      for (int fi = 0; fi < 32; ++fi) {
        float2 h = zbase[fi * 256 + 128];
        const float4* wp = reinterpret_cast<const float4*>(wb + fi * 32);
        #pragma unroll
        for (int q = 0; q < 8; ++q) {
          float4 v = wp[q];
          acc[2 * q].x     += h.x * v.x - h.y * v.y;
          acc[2 * q].y     += h.x * v.y + h.y * v.x;
          acc[2 * q + 1].x += h.x * v.z - h.y * v.w;
          acc[2 * q + 1].y += h.x * v.w + h.y * v.z;
        }
      }
    } else {
      const bool cj = pos > 128;      // mirror region: multiply by conj(w)
      int kp;
      if (!cj) kp = pos;
      else {
        const int ll = pos & 63, rr = pos >> 6;
        kp = (ll == 0) ? (256 - pos)
                       : (brv6((64 - brv6(ll)) & 63) + ((3 - rr) << 6));
      }
      const float sg = cj ? -1.f : 1.f;
      #pragma unroll 2
      for (int fi = 0; fi < 32; ++fi) {
        float2 h = zbase[fi * 256 + pos];
        const float hxs = sg * h.x, hys = sg * h.y;
        const float4* wp = reinterpret_cast<const float4*>(
            WeqM + ((size_t)((l * 32 + fi) * 128 + kp)) * 32 + hf * 16);
        #pragma unroll
        for (int q = 0; q < 8; ++q) {
          float4 v = wp[q];
          acc[2 * q].x     += h.x * v.x - hys * v.y;
          acc[2 * q].y     += hxs * v.y + h.y * v.x;
          acc[2 * q + 1].x += h.x * v.z - hys * v.w;
          acc[2 * q + 1].y += hxs * v.w + h.y * v.z;
        }
      }
      if (pos == 0) {
        #pragma unroll
        for (int j = 0; j < 16; ++j) {
          float be = b_eq[l * 32 + hf * 16 + j];
          acc[j].x += be;   // bias hits both packed rows at bin 0
          acc[j].y += be;
        }
      }
    }
    // column pos is private to this lane pair; pass1 reads cols 128..255,
    // pass0 wrote cols 0..127 -> disjoint, no sync needed.
    #pragma unroll
    for (int j = 0; j < 16; ++j)
      zbase[(hf * 16 + j) * 256 + pos] = acc[j];
  }
}

// ---- team FFT phase: 4 waves x 8 feature-tasks; last -> reduce into red ----
__device__ __forceinline__ void teamFFT(
    float2* __restrict__ zbase, const float2 tw[5], float2 u1, float2 u2,
    float2 u3, int tw_wave, int lane, bool last, float2* __restrict__ redc) {
  float ls0 = 0.f, ls1 = 0.f;
  #pragma unroll 1
  for (int j = 0; j < 8; ++j) {
    const int f = tw_wave + 4 * j;
    float2* zrow = zbase + f * 256;
    float2 z[4];
    #pragma unroll
    for (int r = 0; r < 4; ++r) z[r] = zrow[lane + (r << 6)];
    inv256(z, tw, u1, u2, u3, lane);   // z[r] = (rowA[4lane+r], rowB[4lane+r])
    if (!last) {
      #pragma unroll
      for (int r = 0; r < 4; ++r) {
        z[r].x = swishf(z[r].x);
        z[r].y = swishf(z[r].y);
      }
      fwd256(z, tw, u1, u2, u3, lane);
      #pragma unroll
      for (int r = 0; r < 4; ++r) zrow[lane + (r << 6)] = z[r];
    } else {
      #pragma unroll
      for (int r = 0; r < 4; ++r) {
        ls0 += swishf(z[r].x);
        ls1 += swishf(z[r].y);
      }
    }
  }
  if (last) {
    #pragma unroll
    for (int m = 32; m >= 1; m >>= 1) {
      ls0 += __shfl_xor(ls0, m);
      ls1 += __shfl_xor(ls1, m);
    }
    if (lane == 0) redc[tw_wave] = make_float2(ls0, ls1);
  }
}

// ---------------- main fused kernel: 256 blocks x 512 threads, 2 teams ----------------
__global__ __launch_bounds__(512, 1) void gcnn_main(
    const float* __restrict__ x_in, const float* __restrict__ b_symm,
    const float* __restrict__ b_eq, const float2* __restrict__ Ws_hat,
    const float2* __restrict__ WeqM, const float2* __restrict__ Weq128,
    float* __restrict__ out) {
  __shared__ float2 Zs[2 * 8192];   // [team][fi][pos], 128 KB
  __shared__ float2 fxz[2 * 256];   // packed input spectra per team
  __shared__ float2 red[2][4];      // [team][wave-in-team] partial sums

  const int tid = threadIdx.x;
  const int team = tid >> 8;         // 0: waves 0-3, 1: waves 4-7
  const int tp = tid & 255;          // tid within team
  const int tww = (tid >> 6) & 3;    // wave within team
  const int lane = tid & 63;
  const int brev = brv6(lane);
  float2* const zbase = Zs + team * 8192;

  // per-lane FFT constants
  float2 tw[5];
  #pragma unroll
  for (int s = 0; s < 5; ++s) {
    const int half = 32 >> s;
    float ang = -0.09817477042468103871f * (float)((lane & (half - 1)) << s);
    __sincosf(ang, &tw[s].y, &tw[s].x);
  }
  float2 u1;
  {
    float ang = -0.02454369260617025968f * (float)brev;
    __sincosf(ang, &u1.y, &u1.x);
  }
  const float2 u2 = cmul(u1, u1);
  const float2 u3 = cmul(u2, u1);
  const int rbl = brv6((64 - brev) & 63);   // mirror lane (for lane != 0)

  // Phase 0a: wave 0 of each team packs its 2 rows, FFTs, stores S-layout
  if (tww == 0) {
    const float* xa = x_in + (size_t)(blockIdx.x * 4 + 2 * team) * NG;
    float4 va = reinterpret_cast<const float4*>(xa)[lane];
    float4 vb = reinterpret_cast<const float4*>(xa + NG)[lane];
    float2 z[4] = {{va.x, vb.x}, {va.y, vb.y}, {va.z, vb.z}, {va.w, vb.w}};
    fwd256(z, tw, u1, u2, u3, lane);
    #pragma unroll
    for (int r = 0; r < 4; ++r) fxz[team * 256 + lane + (r << 6)] = z[r];
  }
  __syncthreads();

  // Phase 0b: Z0[f][s] = Zx[mirror(s)] * WsHat[f][s] (+256*bs*(1+i) at s=0)
  {
    const float2* fx = fxz + team * 256;
    #pragma unroll 1
    for (int j = 0; j < 8; ++j) {
      const int f = tww + 4 * j;
      const float bs = 256.f * b_symm[f];
      const float2* wsf = Ws_hat + f * 256;
      #pragma unroll
      for (int r = 0; r < 4; ++r) {
        const int s = lane + (r << 6);
        const int m = (lane == 0) ? (((4 - r) & 3) << 6) : (rbl + ((3 - r) << 6));
        float2 o = cmul(fx[m], wsf[s]);
        if (s == 0) { o.x += bs; o.y += bs; }
        zbase[f * 256 + s] = o;
      }
    }
  }
  __syncthreads();

  // Pipelined slots: odd slots {T0:G, T1:F}, even slots {T0:F, T1:G}
  // s1
  if (team == 0) teamGEMM(zbase, WeqM, Weq128, b_eq, 0, tp);
  __syncthreads();
  // s2
  if (team == 0) teamFFT(zbase, tw, u1, u2, u3, tww, lane, false, red[0]);
  else           teamGEMM(zbase, WeqM, Weq128, b_eq, 0, tp);
  __syncthreads();
  // s3
  if (team == 0) teamGEMM(zbase, WeqM, Weq128, b_eq, 1, tp);
  else           teamFFT(zbase, tw, u1, u2, u3, tww, lane, false, red[1]);
  __syncthreads();
  // s4
  if (team == 0) teamFFT(zbase, tw, u1, u2, u3, tww, lane, false, red[0]);
  else           teamGEMM(zbase, WeqM, Weq128, b_eq, 1, tp);
  __syncthreads();
  // s5
  if (team == 0) teamGEMM(zbase, WeqM, Weq128, b_eq, 2, tp);
  else           teamFFT(zbase, tw, u1, u2, u3, tww, lane, false, red[1]);
  __syncthreads();
  // s6
  if (team == 0) teamFFT(zbase, tw, u1, u2, u3, tww, lane, true, red[0]);
  else           teamGEMM(zbase, WeqM, Weq128, b_eq, 2, tp);
  __syncthreads();
  // s7
  if (team == 1) teamFFT(zbase, tw, u1, u2, u3, tww, lane, true, red[1]);
  __syncthreads();

  if (tid < 4) {
    const int tm = tid >> 1;
    float s = 0.f;
    #pragma unroll
    for (int t4 = 0; t4 < 4; ++t4)
      s += (tid & 1) ? red[tm][t4].y : red[tm][t4].x;
    out[blockIdx.x * 4 + tid] = s * (1.f / 8192.f);
  }
}

extern "C" void kernel_launch(void* const* d_in, const int* in_sizes, int n_in,
                              void* d_out, int out_size, void* d_ws, size_t ws_size,
                              hipStream_t stream) {
  const float* x_in   = (const float*)d_in[0];
  // d_in[1] = perms, d_in[2] = group_algebra: structure hard-coded (cyclic group)
  const float* w_symm = (const float*)d_in[3];
  const float* b_symm = (const float*)d_in[4];
  const float* w_eq   = (const float*)d_in[5];
  const float* b_eq   = (const float*)d_in[6];
  float* out = (float*)d_out;

  float2* Ws_hat = (float2*)d_ws;                      // 32*256
  float2* WeqM   = Ws_hat + 32 * 256;                  // 3*32*128*32
  float2* Weq128 = WeqM + (size_t)3 * 32 * 128 * 32;   // 3*32*32  (~3.24 MB total)

  hipLaunchKernelGGL(gcnn_wfft, dim3(776), dim3(256), 0, stream,
                     w_symm, w_eq, Ws_hat, WeqM, Weq128);
  hipLaunchKernelGGL(gcnn_main, dim3(256), dim3(512), 0, stream,
                     x_in, b_symm, b_eq, Ws_hat, WeqM, Weq128, out);
}

// Round 17
// 385.110 us; speedup vs baseline: 1.8925x; 1.0978x over previous
//
#include <hip/hip_runtime.h>

// GCNN via FFT over C_256 — four-step register-FFT edition.
// Spectra: storage position s = 16*k1 + k2 holds bin b = 16*k2 + k1.
// FFT per 16-lane group (4 per wave): 16-pt radix-4 DFTs in registers
// (compile-time indices), per-lane mid twiddles (15 persistent regs),
// 16x16 transpose THROUGH the LDS row (8 ds_write_b128 + 16 ds_read_b64,
// XOR bank swizzle) — no cross-lane shuffles. ~2x fewer VALU and ~6x fewer
// DS ops per transform than the radix-2 shuffle FFT (R8, 177us).
// GEMM: R13's verified sign-folded conj form, weights indexed BY BIN
// (Weq129: bins 0..128), no special cases. Packed Z = rowA + i*rowB.
// Shell: 256 blocks x 512 threads, 2 pairs (4 rows), ~132KB LDS, (512,1).

#define NG 256
#define NLAYER 3
#define LGKM() asm volatile("s_waitcnt lgkmcnt(0)" ::: "memory")

// row-internal float2-index swizzle (breaks the 128B-stride bank pattern)
__device__ __forceinline__ int swp(int e) { return e ^ (((e >> 4) & 7) << 1); }

__device__ __forceinline__ float2 cadd(float2 a, float2 b) { return make_float2(a.x + b.x, a.y + b.y); }
__device__ __forceinline__ float2 csub(float2 a, float2 b) { return make_float2(a.x - b.x, a.y - b.y); }
__device__ __forceinline__ float2 cmul(float2 a, float2 b) {
  return make_float2(a.x * b.x - a.y * b.y, a.x * b.y + a.y * b.x);
}
__device__ __forceinline__ float2 cmulc(float2 a, float2 b) {  // a * conj(b)
  return make_float2(a.x * b.x + a.y * b.y, a.y * b.x - a.x * b.y);
}
__device__ __forceinline__ float swishf(float y) { return y / (1.f + __expf(-y)); }

// ---------------- prep-kernel LDS FFT (proven R1-R14) ----------------
__device__ __forceinline__ int swz(int a) {
  int h = a >> 4;
  return a ^ ((h ^ (h << 1)) & 15);
}

__device__ __forceinline__ void wave_fft256_lds(float2* __restrict__ s,
                                                const float2* __restrict__ tw,
                                                int lane) {
  LGKM();
  #pragma unroll
  for (int t = 0; t < 4; ++t) {
    int i = t * 64 + lane;
    int j = (int)(__brev((unsigned)i) >> 24);
    if (j > i) {
      float2 a = s[swz(i)]; float2 b = s[swz(j)];
      s[swz(i)] = b; s[swz(j)] = a;
    }
  }
  LGKM();
  #pragma unroll
  for (int st = 0; st < 8; ++st) {
    const int half = 1 << st;
    const int tshift = 7 - st;
    #pragma unroll
    for (int t = 0; t < 2; ++t) {
      int bf = t * 64 + lane;
      int off = bf & (half - 1);
      int blk = bf >> st;
      int i = (blk << (st + 1)) + off;
      int j = i + half;
      float2 wv = tw[swz(off << tshift)];
      float2 u = s[swz(i)];
      float2 v = s[swz(j)];
      float vr = v.x * wv.x - v.y * wv.y;
      float vi = v.x * wv.y + v.y * wv.x;
      s[swz(i)] = make_float2(u.x + vr, u.y + vi);
      s[swz(j)] = make_float2(u.x - vr, u.y - vi);
    }
    LGKM();
  }
}

// weight FFT prep. Ws_hat[f][s]: full 256 storage positions (linear layout);
// Weq129[l][fi][bin 0..128][fo]: indexed by BIN (mirror bins via conj in GEMM).
__global__ __launch_bounds__(256) void gcnn_wfft(
    const float* __restrict__ w_symm, const float* __restrict__ w_eq,
    float2* __restrict__ Ws_hat, float2* __restrict__ Weq129) {
  __shared__ float2 fbw[4][256];
  __shared__ float2 twl[256];
  const int tid = threadIdx.x;
  const int w = tid >> 6;
  const int lane = tid & 63;
  {
    float a = (float)tid * 0.0245436926f;  // 2*pi/256
    twl[swz(tid)] = make_float2(cosf(a), -sinf(a));
  }
  __syncthreads();
  const int task = blockIdx.x * 4 + w;  // 776*4 = 3104 tasks exactly
  if (task < 32) {
    const int f = task;
    for (int g = lane; g < 256; g += 64)
      fbw[w][swz(g)] = make_float2(w_symm[g * 32 + f], 0.f);
    wave_fft256_lds(&fbw[w][0], twl, lane);
    for (int k = lane; k < 256; k += 64) {
      int sk = 16 * (k & 15) + (k >> 4);   // storage of bin k
      Ws_hat[f * 256 + sk] = fbw[w][swz(k)];
    }
  } else {
    const int idx = task - 32;
    const int l = idx >> 10;
    const int fi = (idx >> 5) & 31;
    const int fo = idx & 31;
    for (int g = lane; g < 256; g += 64)
      fbw[w][swz(g)] = make_float2(w_eq[((size_t)(l * 256 + g) * 32 + fi) * 32 + fo] * (1.f / 256.f), 0.f);
    wave_fft256_lds(&fbw[w][0], twl, lane);
    for (int k = lane; k < 129; k += 64)
      Weq129[((size_t)((l * 32 + fi) * 129 + k)) * 32 + fo] = fbw[w][swz(k)];
  }
}

// ---------------- 16-pt DFT in registers (radix-4 x radix-4, unrolled) ----------------
template <bool INV>
__device__ __forceinline__ void dft16(float2 z[16]) {
  const float C1 = 0.92387953251f, S1 = 0.38268343236f, C2 = 0.70710678119f;
  float2 b[16];
  #pragma unroll
  for (int j1 = 0; j1 < 4; ++j1) {
    float2 a0 = z[j1], a1 = z[j1 + 4], a2 = z[j1 + 8], a3 = z[j1 + 12];
    float2 t0 = cadd(a0, a2), t1 = cadd(a1, a3);
    float2 t2 = csub(a0, a2), t3 = csub(a1, a3);
    b[j1 * 4 + 0] = cadd(t0, t1);
    b[j1 * 4 + 2] = csub(t0, t1);
    if (!INV) {
      b[j1 * 4 + 1] = make_float2(t2.x + t3.y, t2.y - t3.x);  // t2 - i t3
      b[j1 * 4 + 3] = make_float2(t2.x - t3.y, t2.y + t3.x);
    } else {
      b[j1 * 4 + 1] = make_float2(t2.x - t3.y, t2.y + t3.x);  // t2 + i t3
      b[j1 * 4 + 3] = make_float2(t2.x + t3.y, t2.y - t3.x);
    }
  }
  const float sI = INV ? 1.f : -1.f;
  auto tw = [](float2 v, float cr, float ci) {
    return make_float2(v.x * cr - v.y * ci, v.x * ci + v.y * cr);
  };
  b[5]  = tw(b[5],  C1, sI * S1);                                   // e1
  b[6]  = tw(b[6],  C2, sI * C2);                                   // e2
  b[7]  = tw(b[7],  S1, sI * C1);                                   // e3
  b[9]  = tw(b[9],  C2, sI * C2);                                   // e2
  b[10] = INV ? make_float2(-b[10].y, b[10].x)
              : make_float2(b[10].y, -b[10].x);                     // e4 = -i / +i
  b[11] = tw(b[11], -C2, sI * C2);                                  // e6
  b[13] = tw(b[13], S1, sI * C1);                                   // e3
  b[14] = tw(b[14], -C2, sI * C2);                                  // e6
  b[15] = tw(b[15], -C1, -sI * S1);                                 // e9
  #pragma unroll
  for (int k1 = 0; k1 < 4; ++k1) {
    float2 a0 = b[k1], a1 = b[4 + k1], a2 = b[8 + k1], a3 = b[12 + k1];
    float2 t0 = cadd(a0, a2), t1 = cadd(a1, a3);
    float2 t2 = csub(a0, a2), t3 = csub(a1, a3);
    z[k1]      = cadd(t0, t1);
    z[k1 + 8]  = csub(t0, t1);
    if (!INV) {
      z[k1 + 4]  = make_float2(t2.x + t3.y, t2.y - t3.x);
      z[k1 + 12] = make_float2(t2.x - t3.y, t2.y + t3.x);
    } else {
      z[k1 + 4]  = make_float2(t2.x - t3.y, t2.y + t3.x);
      z[k1 + 12] = make_float2(t2.x + t3.y, t2.y - t3.x);
    }
  }
}

// ---- row I/O helpers (c = lane&15). Contiguous 16-reg segment at 16c. ----
__device__ __forceinline__ void rowstore16(float2* __restrict__ row,
                                           const float2 z[16], int c) {
  const int xm = (c & 7) << 1;
  #pragma unroll
  for (int i = 0; i < 8; ++i) {
    int pe = (16 * c + 2 * i) ^ xm;
    *reinterpret_cast<float4*>(row + pe) =
        make_float4(z[2 * i].x, z[2 * i].y, z[2 * i + 1].x, z[2 * i + 1].y);
  }
}
__device__ __forceinline__ void rowload16(const float2* __restrict__ row,
                                          float2 z[16], int c) {
  const int xm = (c & 7) << 1;
  #pragma unroll
  for (int i = 0; i < 8; ++i) {
    float4 v = *reinterpret_cast<const float4*>(row + ((16 * c + 2 * i) ^ xm));
    z[2 * i]     = make_float2(v.x, v.y);
    z[2 * i + 1] = make_float2(v.z, v.w);
  }
}
__device__ __forceinline__ void rowload_strided(const float2* __restrict__ row,
                                                float2 z[16], int c) {
  #pragma unroll
  for (int k = 0; k < 16; ++k)
    z[k] = row[(16 * k + c) ^ ((k & 7) << 1)];
}

// Forward 256 within a 16-lane group. Entry: z[j] = x[16j + c].
// Exit: z[k2] = X[16*k2 + k1] at lane k1 = c (store at s = 16c + k2).
__device__ __forceinline__ void fwd256g(float2 z[16], const float2 ua[15],
                                        float2* __restrict__ row, int c) {
  dft16<false>(z);
  #pragma unroll
  for (int k = 1; k < 16; ++k) z[k] = cmul(z[k], ua[k - 1]);
  LGKM();
  rowstore16(row, z, c);
  LGKM();
  rowload_strided(row, z, c);
  dft16<false>(z);
}

// Inverse (unnormalized). Entry: z[k2] = Y[16*k2 + k1], lane k1 = c.
// Exit: z[j] = y[16j + c].
__device__ __forceinline__ void inv256g(float2 z[16], const float2 ua[15],
                                        float2* __restrict__ row, int c) {
  dft16<true>(z);
  #pragma unroll
  for (int k = 1; k < 16; ++k) z[k] = cmulc(z[k], ua[k - 1]);
  LGKM();
  rowstore16(row, z, c);
  LGKM();
  rowload_strided(row, z, c);
  dft16<true>(z);
}

// ---------------- main fused kernel: 256 blocks x 512 threads, 2 pairs ----------------
__global__ __launch_bounds__(512, 1) void gcnn_main(
    const float* __restrict__ x_in, const float* __restrict__ b_symm,
    const float* __restrict__ b_eq, const float2* __restrict__ Ws_hat,
    const float2* __restrict__ Weq129, float* __restrict__ out) {
  __shared__ float2 Zs[2 * 8192];   // [pair][fi][pos(swizzled)], 128 KB
  __shared__ float2 fxz[2 * 256];   // mirrored packed input spectra per pair
  __shared__ float2 red[2][8];

  const int tid = threadIdx.x;
  const int w = tid >> 6;
  const int lane = tid & 63;
  const int c16 = lane & 15;
  const int grp = (lane >> 4) & 3;

  // persistent per-lane mid twiddles u^k = W256^(c16 * k), k = 1..15
  float2 ua[15];
  #pragma unroll
  for (int k = 1; k < 16; ++k) {
    float ang = -0.02454369260617025968f * (float)(c16 * k);
    float sv, cv;
    __sincosf(ang, &sv, &cv);
    ua[k - 1] = make_float2(cv, sv);
  }

  // Phase 0a: wave 0, groups 0-1: packed FFT of each pair's 2 rows,
  // then scatter MIRRORED spectrum into fxz (value of bin mirror(bin(s)) at s).
  if (w == 0 && lane < 32) {
    float2* frow = fxz + grp * 256;
    const float* xa = x_in + (size_t)(blockIdx.x * 4 + 2 * grp) * NG;
    float2 z[16];
    #pragma unroll
    for (int j = 0; j < 16; ++j)
      z[j] = make_float2(xa[16 * j + c16], xa[NG + 16 * j + c16]);
    fwd256g(z, ua, frow, c16);
    LGKM();
    #pragma unroll
    for (int k2 = 0; k2 < 16; ++k2) {
      int b = 16 * k2 + c16;            // bin held in this reg
      int mb = (256 - b) & 255;         // mirror bin
      int ms = 16 * (mb & 15) + (mb >> 4);
      frow[swp(ms)] = z[k2];
    }
  }
  __syncthreads();

  // Phase 0b: Z0[p][f][s] = fxzMirr[p][s] * WsHat[f][s]  (+256*bs*(1+i) at s=0)
  #pragma unroll 1
  for (int p = 0; p < 2; ++p) {
    const float2* fx = fxz + p * 256;
    #pragma unroll 1
    for (int j = 0; j < 4; ++j) {
      const int f = w + 8 * j;
      const float bs = 256.f * b_symm[f];
      const float2* wsf = Ws_hat + f * 256;
      float2* zrow = Zs + p * 8192 + f * 256;
      #pragma unroll
      for (int r = 0; r < 4; ++r) {
        const int s = lane + (r << 6);
        float2 o = cmul(fx[swp(s)], wsf[s]);
        if (s == 0) { o.x += bs; o.y += bs; }
        zrow[swp(s)] = o;
      }
    }
  }
  __syncthreads();

  #pragma unroll 1
  for (int l = 0; l < NLAYER; ++l) {
    const bool last = (l == NLAYER - 1);

    // ---- spectral GEMM (per pair, bin-indexed weights, sign-folded conj) ----
    {
      const int s = tid >> 1;
      const int hf = tid & 1;
      const int sp = swp(s);
      const int b = 16 * (s & 15) + (s >> 4);   // bin at storage s
      const int cj = b > 128;
      const int kp = cj ? 256 - b : b;
      const float sg = cj ? -1.f : 1.f;
      #pragma unroll 1
      for (int p = 0; p < 2; ++p) {
        float2* zslab = Zs + p * 8192;
        float2 acc[16];
        #pragma unroll
        for (int j = 0; j < 16; ++j) acc[j] = make_float2(0.f, 0.f);
        #pragma unroll 2
        for (int fi = 0; fi < 32; ++fi) {
          float2 h = zslab[fi * 256 + sp];
          const float hxs = sg * h.x, hys = sg * h.y;
          const float4* wp = reinterpret_cast<const float4*>(
              Weq129 + ((size_t)((l * 32 + fi) * 129 + kp)) * 32 + hf * 16);
          #pragma unroll
          for (int q = 0; q < 8; ++q) {
            float4 v = wp[q];
            acc[2 * q].x     += h.x * v.x - hys * v.y;
            acc[2 * q].y     += hxs * v.y + h.y * v.x;
            acc[2 * q + 1].x += h.x * v.z - hys * v.w;
            acc[2 * q + 1].y += hxs * v.w + h.y * v.z;
          }
        }
        if (s == 0) {
          #pragma unroll
          for (int j = 0; j < 16; ++j) {
            float be = b_eq[l * 32 + hf * 16 + j];
            acc[j].x += be;
            acc[j].y += be;
          }
        }
        #pragma unroll
        for (int j = 0; j < 16; ++j)
          zslab[(hf * 16 + j) * 256 + sp] = acc[j];   // column s: lane-pair private
      }
    }
    __syncthreads();

    // ---- FFT phase: 2 slots x 4 group-transforms per wave ----
    float lsx[2] = {0.f, 0.f}, lsy[2] = {0.f, 0.f};
    #pragma unroll 1
    for (int q = 0; q < 2; ++q) {     // slot q == pair q
      const int f = 4 * w + grp;
      float2* row = Zs + q * 8192 + f * 256;
      float2 z[16];
      rowload16(row, z, c16);
      inv256g(z, ua, row, c16);       // z[j] = (rowA, rowB) time samples
      if (!last) {
        #pragma unroll
        for (int j = 0; j < 16; ++j) {
          z[j].x = swishf(z[j].x);
          z[j].y = swishf(z[j].y);
        }
        fwd256g(z, ua, row, c16);
        LGKM();
        rowstore16(row, z, c16);
      } else {
        #pragma unroll
        for (int j = 0; j < 16; ++j) {
          lsx[q] += swishf(z[j].x);
          lsy[q] += swishf(z[j].y);
        }
      }
    }
    if (last) {
      #pragma unroll
      for (int m = 32; m >= 1; m >>= 1) {
        lsx[0] += __shfl_xor(lsx[0], m);
        lsy[0] += __shfl_xor(lsy[0], m);
        lsx[1] += __shfl_xor(lsx[1], m);
        lsy[1] += __shfl_xor(lsy[1], m);
      }
      if (lane == 0) {
        red[0][w] = make_float2(lsx[0], lsy[0]);
        red[1][w] = make_float2(lsx[1], lsy[1]);
      }
    }
    __syncthreads();
  }

  if (tid < 4) {
    const int pp = tid >> 1;
    float s = 0.f;
    #pragma unroll
    for (int ww = 0; ww < 8; ++ww)
      s += (tid & 1) ? red[pp][ww].y : red[pp][ww].x;
    out[blockIdx.x * 4 + tid] = s * (1.f / 8192.f);
  }
}

extern "C" void kernel_launch(void* const* d_in, const int* in_sizes, int n_in,
                              void* d_out, int out_size, void* d_ws, size_t ws_size,
                              hipStream_t stream) {
  const float* x_in   = (const float*)d_in[0];
  // d_in[1] = perms, d_in[2] = group_algebra: structure hard-coded (cyclic group)
  const float* w_symm = (const float*)d_in[3];
  const float* b_symm = (const float*)d_in[4];
  const float* w_eq   = (const float*)d_in[5];
  const float* b_eq   = (const float*)d_in[6];
  float* out = (float*)d_out;

  float2* Ws_hat = (float2*)d_ws;                      // 32*256 (64KB)
  float2* Weq129 = Ws_hat + 32 * 256;                  // 3*32*129*32 (~3.17MB)

  hipLaunchKernelGGL(gcnn_wfft, dim3(776), dim3(256), 0, stream,
                     w_symm, w_eq, Ws_hat, Weq129);
  hipLaunchKernelGGL(gcnn_main, dim3(256), dim3(512), 0, stream,
                     x_in, b_symm, b_eq, Ws_hat, Weq129, out);
}